// Round 1
// baseline (2439.518 us; speedup 1.0000x reference)
//
#include <hip/hip_runtime.h>
#include <hip/hip_bf16.h>

#define N_NODES 10000
#define N_EDGES 320000
#define N_GRAPHS 64
#define DIM 256
#define ADIM 118
#define OUTD 100

// h[n][d] = sum_a atomic_num[n][a] * W_node[a][d] + b_node[d]
__global__ __launch_bounds__(256) void node_embed_k(
    const float* __restrict__ an, const float* __restrict__ Wn,
    const float* __restrict__ bn, float* __restrict__ h) {
    __shared__ float xs[ADIM];
    int n = blockIdx.x;
    int tid = threadIdx.x;
    if (tid < ADIM) xs[tid] = an[n * ADIM + tid];
    __syncthreads();
    float acc = bn[tid];
    #pragma unroll 2
    for (int a = 0; a < ADIM; ++a) acc += xs[a] * Wn[a * DIM + tid];
    h[n * DIM + tid] = acc;
}

// one wave per edge; lane handles 4 consecutive d's.
// m = relu(h[src] + len*W_edge + b_edge); atomicAdd into agg[dst]
__global__ __launch_bounds__(256) void edge_scatter_k(
    const float* __restrict__ h, float* __restrict__ agg,
    const int* __restrict__ src, const int* __restrict__ dst,
    const float* __restrict__ len, const float* __restrict__ We,
    const float* __restrict__ be) {
    int tid = blockIdx.x * 256 + threadIdx.x;
    int j = tid >> 6;
    int lane = tid & 63;
    if (j >= N_EDGES) return;
    int s = src[j];
    int d = dst[j];
    float l = len[j];
    int c = lane << 2;
    const float4 hv = *(const float4*)(h + (size_t)s * DIM + c);
    const float4 w  = *(const float4*)(We + c);
    const float4 bb = *(const float4*)(be + c);
    float m0 = fmaxf(hv.x + l * w.x + bb.x, 0.f);
    float m1 = fmaxf(hv.y + l * w.y + bb.y, 0.f);
    float m2 = fmaxf(hv.z + l * w.z + bb.z, 0.f);
    float m3 = fmaxf(hv.w + l * w.w + bb.w, 0.f);
    float* ap = agg + (size_t)d * DIM + c;
    atomicAdd(ap + 0, m0);
    atomicAdd(ap + 1, m1);
    atomicAdd(ap + 2, m2);
    atomicAdd(ap + 3, m3);
}

// hout = ((1+eps)*h + agg) @ W + b  ; 16 node-rows per block
__global__ __launch_bounds__(256) void node_update_k(
    const float* __restrict__ h, const float* __restrict__ agg,
    float* __restrict__ hout, const float* __restrict__ W,
    const float* __restrict__ b, const float* __restrict__ eps_ptr, int layer) {
    __shared__ float xs[16][DIM];
    const float eps1 = 1.0f + eps_ptr[layer];
    const int block_row = blockIdx.x * 16;
    const int tid = threadIdx.x;
    #pragma unroll
    for (int i = 0; i < 16; ++i) {
        int idx = (block_row + i) * DIM + tid;
        xs[i][tid] = eps1 * h[idx] + agg[idx];
    }
    __syncthreads();
    float acc[16];
    #pragma unroll
    for (int m = 0; m < 16; ++m) acc[m] = 0.f;
    for (int k = 0; k < DIM; ++k) {
        float w = W[k * DIM + tid];
        #pragma unroll
        for (int m = 0; m < 16; ++m) acc[m] += xs[m][k] * w;
    }
    float bb = b[tid];
    #pragma unroll
    for (int m = 0; m < 16; ++m)
        hout[(block_row + m) * DIM + tid] = acc[m] + bb;
}

// feat[g] += h[n]  (one wave per node, float4 per lane)
__global__ __launch_bounds__(256) void pool_k(
    const float* __restrict__ h, const int* __restrict__ gid,
    float* __restrict__ feat) {
    int tid = blockIdx.x * 256 + threadIdx.x;
    int n = tid >> 6;
    int lane = tid & 63;
    if (n >= N_NODES) return;
    int g = gid[n];
    int c = lane << 2;
    const float4 hv = *(const float4*)(h + (size_t)n * DIM + c);
    float* fp = feat + (size_t)g * DIM + c;
    atomicAdd(fp + 0, hv.x);
    atomicAdd(fp + 1, hv.y);
    atomicAdd(fp + 2, hv.z);
    atomicAdd(fp + 3, hv.w);
}

__global__ __launch_bounds__(256) void minmax_k(
    const float* __restrict__ feat, float* __restrict__ mm) {
    float mn = 3.4e38f, mx = -3.4e38f;
    for (int i = threadIdx.x; i < N_GRAPHS * DIM; i += 256) {
        float v = feat[i];
        mn = fminf(mn, v);
        mx = fmaxf(mx, v);
    }
    // wave reduce (width 64)
    #pragma unroll
    for (int off = 32; off > 0; off >>= 1) {
        mn = fminf(mn, __shfl_down(mn, off, 64));
        mx = fmaxf(mx, __shfl_down(mx, off, 64));
    }
    __shared__ float smn[4], smx[4];
    int wave = threadIdx.x >> 6;
    int lane = threadIdx.x & 63;
    if (lane == 0) { smn[wave] = mn; smx[wave] = mx; }
    __syncthreads();
    if (threadIdx.x == 0) {
        mn = smn[0]; mx = smx[0];
        #pragma unroll
        for (int w = 1; w < 4; ++w) {
            mn = fminf(mn, smn[w]);
            mx = fmaxf(mx, smx[w]);
        }
        mm[0] = mn;
        mm[1] = mx;
    }
}

// out[g][o] = ((feat[g]-mn)*inv) @ W_mlp + b_mlp
__global__ __launch_bounds__(256) void head_k(
    const float* __restrict__ feat, const float* __restrict__ mm,
    const float* __restrict__ Wm, const float* __restrict__ bm,
    float* __restrict__ out, const float* __restrict__ epsp) {
    int tid = blockIdx.x * 256 + threadIdx.x;
    if (tid >= N_GRAPHS * OUTD) return;
    int g = tid / OUTD;
    int o = tid % OUTD;
    float mn = mm[0], mx = mm[1];
    float inv = 1.f / (epsp[0] + mx - mn);
    float acc = 0.f;
    for (int d = 0; d < DIM; ++d)
        acc += (feat[g * DIM + d] - mn) * Wm[d * OUTD + o];
    out[tid] = acc * inv + bm[o];
}

extern "C" void kernel_launch(void* const* d_in, const int* in_sizes, int n_in,
                              void* d_out, int out_size, void* d_ws, size_t ws_size,
                              hipStream_t stream) {
    const float* atomic_num = (const float*)d_in[0];
    const float* length     = (const float*)d_in[1];
    const int*   src        = (const int*)d_in[2];
    const int*   dst        = (const int*)d_in[3];
    const int*   gid        = (const int*)d_in[4];
    const float* W_node     = (const float*)d_in[5];
    const float* b_node     = (const float*)d_in[6];
    const float* W_edge     = (const float*)d_in[7];
    const float* b_edge     = (const float*)d_in[8];
    const float* gine_eps   = (const float*)d_in[9];
    const float* W_gnn      = (const float*)d_in[10];
    const float* b_gnn      = (const float*)d_in[11];
    const float* eps_param  = (const float*)d_in[12];
    const float* W_mlp      = (const float*)d_in[13];
    const float* b_mlp      = (const float*)d_in[14];
    float* out = (float*)d_out;

    float* h0   = (float*)d_ws;                 // N*D
    float* h1   = h0 + (size_t)N_NODES * DIM;   // N*D
    float* agg  = h1 + (size_t)N_NODES * DIM;   // N*D
    float* feat = agg + (size_t)N_NODES * DIM;  // G*D
    float* mm   = feat + (size_t)N_GRAPHS * DIM; // 2

    node_embed_k<<<N_NODES, 256, 0, stream>>>(atomic_num, W_node, b_node, h0);

    // GINE layer 0
    hipMemsetAsync(agg, 0, (size_t)N_NODES * DIM * sizeof(float), stream);
    edge_scatter_k<<<(N_EDGES * 64) / 256, 256, 0, stream>>>(
        h0, agg, src, dst, length, W_edge, b_edge);
    node_update_k<<<N_NODES / 16, 256, 0, stream>>>(
        h0, agg, h1, W_gnn, b_gnn, gine_eps, 0);

    // GINE layer 1
    hipMemsetAsync(agg, 0, (size_t)N_NODES * DIM * sizeof(float), stream);
    edge_scatter_k<<<(N_EDGES * 64) / 256, 256, 0, stream>>>(
        h1, agg, src, dst, length, W_edge, b_edge);
    node_update_k<<<N_NODES / 16, 256, 0, stream>>>(
        h1, agg, h0, W_gnn + DIM * DIM, b_gnn + DIM, gine_eps, 1);

    // pooling + normalize + head
    hipMemsetAsync(feat, 0, (size_t)N_GRAPHS * DIM * sizeof(float), stream);
    pool_k<<<(N_NODES * 64) / 256, 256, 0, stream>>>(h0, gid, feat);
    minmax_k<<<1, 256, 0, stream>>>(feat, mm);
    head_k<<<(N_GRAPHS * OUTD + 255) / 256, 256, 0, stream>>>(
        feat, mm, W_mlp, b_mlp, out, eps_param);
}

// Round 2
// 414.582 us; speedup vs baseline: 5.8843x; 5.8843x over previous
//
#include <hip/hip_runtime.h>
#include <hip/hip_bf16.h>

#define N_NODES 10000
#define N_EDGES 320000
#define N_GRAPHS 64
#define DIM 256
#define ADIM 118
#define OUTD 100

// ---------- node embedding: h = atomic_num @ W_node + b_node ----------
// 16 node-rows per block; W_node read once per block (625x reuse -> L2)
__global__ __launch_bounds__(256) void node_embed_k(
    const float* __restrict__ an, const float* __restrict__ Wn,
    const float* __restrict__ bn, float* __restrict__ h) {
    __shared__ float xs[16][ADIM + 2];
    const int block_row = blockIdx.x * 16;
    const int tid = threadIdx.x;
    #pragma unroll
    for (int r = 0; r < 16; ++r) {
        if (tid < ADIM) xs[r][tid] = an[(block_row + r) * ADIM + tid];
    }
    __syncthreads();
    float acc[16];
    #pragma unroll
    for (int m = 0; m < 16; ++m) acc[m] = 0.f;
    for (int k = 0; k < ADIM; ++k) {
        float w = Wn[k * DIM + tid];
        #pragma unroll
        for (int m = 0; m < 16; ++m) acc[m] += xs[m][k] * w;
    }
    float bb = bn[tid];
    #pragma unroll
    for (int m = 0; m < 16; ++m)
        h[(block_row + m) * DIM + tid] = acc[m] + bb;
}

// ---------- CSR build ----------
__global__ __launch_bounds__(256) void hist_k(
    const int* __restrict__ dst, int* __restrict__ counts) {
    int j = blockIdx.x * 256 + threadIdx.x;
    if (j < N_EDGES) atomicAdd(&counts[dst[j]], 1);
}

// single-block exclusive scan over counts[N] -> row_start[N+1], cursor[N]
__global__ __launch_bounds__(1024) void scan_k(
    const int* __restrict__ counts, int* __restrict__ row_start,
    int* __restrict__ cursor) {
    __shared__ int tile[1024];
    __shared__ int carry;
    const int tid = threadIdx.x;
    if (tid == 0) carry = 0;
    __syncthreads();
    for (int base = 0; base < N_NODES; base += 1024) {
        int i = base + tid;
        int v = (i < N_NODES) ? counts[i] : 0;
        tile[tid] = v;
        __syncthreads();
        for (int off = 1; off < 1024; off <<= 1) {
            int t = (tid >= off) ? tile[tid - off] : 0;
            __syncthreads();
            tile[tid] += t;
            __syncthreads();
        }
        int incl = tile[tid];
        int total = tile[1023];
        int base_off = carry;
        if (i < N_NODES) {
            int e = base_off + incl - v;
            row_start[i] = e;
            cursor[i] = e;
        }
        __syncthreads();
        if (tid == 0) carry += total;
        __syncthreads();
    }
    if (tid == 0) row_start[N_NODES] = carry;
}

// pack (src, length-bits) into CSR slots
__global__ __launch_bounds__(256) void fill_k(
    const int* __restrict__ src, const int* __restrict__ dst,
    const float* __restrict__ len, int* __restrict__ cursor,
    int2* __restrict__ epack) {
    int j = blockIdx.x * 256 + threadIdx.x;
    if (j >= N_EDGES) return;
    int d = dst[j];
    int pos = atomicAdd(&cursor[d], 1);
    epack[pos] = make_int2(src[j], __float_as_int(len[j]));
}

// ---------- fused gather-aggregate: x[i] = (1+eps)*h[i] + sum_j relu(h[src]+e) ----------
// one wave per node; lane handles 4 consecutive dims
__global__ __launch_bounds__(256) void gather_agg_k(
    const float* __restrict__ h, const int* __restrict__ row_start,
    const int2* __restrict__ epack, const float* __restrict__ We,
    const float* __restrict__ be, const float* __restrict__ epsp, int layer,
    float* __restrict__ x) {
    const int node = blockIdx.x * 4 + (threadIdx.x >> 6);
    const int lane = threadIdx.x & 63;
    const int c = lane << 2;
    const float4 w  = *(const float4*)(We + c);
    const float4 bb = *(const float4*)(be + c);
    float4 acc = {0.f, 0.f, 0.f, 0.f};
    const int lo = row_start[node];
    const int hi = row_start[node + 1];
    for (int b = lo; b < hi; b += 64) {
        int cnt = min(64, hi - b);
        int sj = 0;
        float lj = 0.f;
        if (lane < cnt) {
            int2 p = epack[b + lane];
            sj = p.x;
            lj = __int_as_float(p.y);
        }
        for (int t = 0; t < cnt; ++t) {
            int s   = __shfl(sj, t, 64);
            float l = __shfl(lj, t, 64);
            const float4 hv = *(const float4*)(h + (size_t)s * DIM + c);
            acc.x += fmaxf(hv.x + l * w.x + bb.x, 0.f);
            acc.y += fmaxf(hv.y + l * w.y + bb.y, 0.f);
            acc.z += fmaxf(hv.z + l * w.z + bb.z, 0.f);
            acc.w += fmaxf(hv.w + l * w.w + bb.w, 0.f);
        }
    }
    const float eps1 = 1.f + epsp[layer];
    const float4 hv = *(const float4*)(h + (size_t)node * DIM + c);
    float4 xo;
    xo.x = eps1 * hv.x + acc.x;
    xo.y = eps1 * hv.y + acc.y;
    xo.z = eps1 * hv.z + acc.z;
    xo.w = eps1 * hv.w + acc.w;
    *(float4*)(x + (size_t)node * DIM + c) = xo;
}

// ---------- node update GEMM: hout = x @ W + b ----------
__global__ __launch_bounds__(256) void node_update_k(
    const float* __restrict__ x, float* __restrict__ hout,
    const float* __restrict__ W, const float* __restrict__ b) {
    __shared__ float xs[16][DIM];
    const int block_row = blockIdx.x * 16;
    const int tid = threadIdx.x;
    #pragma unroll
    for (int i = 0; i < 16; ++i)
        xs[i][tid] = x[(block_row + i) * DIM + tid];
    __syncthreads();
    float acc[16];
    #pragma unroll
    for (int m = 0; m < 16; ++m) acc[m] = 0.f;
    for (int k = 0; k < DIM; ++k) {
        float w = W[k * DIM + tid];
        #pragma unroll
        for (int m = 0; m < 16; ++m) acc[m] += xs[m][k] * w;
    }
    float bb = b[tid];
    #pragma unroll
    for (int m = 0; m < 16; ++m)
        hout[(block_row + m) * DIM + tid] = acc[m] + bb;
}

// ---------- pooling via sorted graph_ids: block per graph, binary search range ----------
__global__ __launch_bounds__(256) void pool_k(
    const float* __restrict__ h, const int* __restrict__ gid,
    float* __restrict__ feat) {
    const int g = blockIdx.x;
    const int d = threadIdx.x;
    int lo = 0, hi = N_NODES;
    while (lo < hi) { int mid = (lo + hi) >> 1; if (gid[mid] < g) lo = mid + 1; else hi = mid; }
    const int start = lo;
    hi = N_NODES;
    while (lo < hi) { int mid = (lo + hi) >> 1; if (gid[mid] < g + 1) lo = mid + 1; else hi = mid; }
    const int end = lo;
    float acc = 0.f;
    for (int n = start; n < end; ++n) acc += h[(size_t)n * DIM + d];
    feat[g * DIM + d] = acc;
}

__global__ __launch_bounds__(256) void minmax_k(
    const float* __restrict__ feat, float* __restrict__ mm) {
    float mn = 3.4e38f, mx = -3.4e38f;
    for (int i = threadIdx.x; i < N_GRAPHS * DIM; i += 256) {
        float v = feat[i];
        mn = fminf(mn, v);
        mx = fmaxf(mx, v);
    }
    #pragma unroll
    for (int off = 32; off > 0; off >>= 1) {
        mn = fminf(mn, __shfl_down(mn, off, 64));
        mx = fmaxf(mx, __shfl_down(mx, off, 64));
    }
    __shared__ float smn[4], smx[4];
    int wave = threadIdx.x >> 6;
    int lane = threadIdx.x & 63;
    if (lane == 0) { smn[wave] = mn; smx[wave] = mx; }
    __syncthreads();
    if (threadIdx.x == 0) {
        mn = smn[0]; mx = smx[0];
        #pragma unroll
        for (int w = 1; w < 4; ++w) {
            mn = fminf(mn, smn[w]);
            mx = fmaxf(mx, smx[w]);
        }
        mm[0] = mn;
        mm[1] = mx;
    }
}

__global__ __launch_bounds__(256) void head_k(
    const float* __restrict__ feat, const float* __restrict__ mm,
    const float* __restrict__ Wm, const float* __restrict__ bm,
    float* __restrict__ out, const float* __restrict__ epsp) {
    int tid = blockIdx.x * 256 + threadIdx.x;
    if (tid >= N_GRAPHS * OUTD) return;
    int g = tid / OUTD;
    int o = tid % OUTD;
    float mn = mm[0], mx = mm[1];
    float inv = 1.f / (epsp[0] + mx - mn);
    float acc = 0.f;
    for (int d = 0; d < DIM; ++d)
        acc += (feat[g * DIM + d] - mn) * Wm[d * OUTD + o];
    out[tid] = acc * inv + bm[o];
}

extern "C" void kernel_launch(void* const* d_in, const int* in_sizes, int n_in,
                              void* d_out, int out_size, void* d_ws, size_t ws_size,
                              hipStream_t stream) {
    const float* atomic_num = (const float*)d_in[0];
    const float* length     = (const float*)d_in[1];
    const int*   src        = (const int*)d_in[2];
    const int*   dst        = (const int*)d_in[3];
    const int*   gid        = (const int*)d_in[4];
    const float* W_node     = (const float*)d_in[5];
    const float* b_node     = (const float*)d_in[6];
    const float* W_edge     = (const float*)d_in[7];
    const float* b_edge     = (const float*)d_in[8];
    const float* gine_eps   = (const float*)d_in[9];
    const float* W_gnn      = (const float*)d_in[10];
    const float* b_gnn      = (const float*)d_in[11];
    const float* eps_param  = (const float*)d_in[12];
    const float* W_mlp      = (const float*)d_in[13];
    const float* b_mlp      = (const float*)d_in[14];
    float* out = (float*)d_out;

    // workspace layout
    float* h0   = (float*)d_ws;                    // N*D
    float* h1   = h0 + (size_t)N_NODES * DIM;      // N*D
    float* x    = h1 + (size_t)N_NODES * DIM;      // N*D
    float* feat = x + (size_t)N_NODES * DIM;       // G*D
    float* mm   = feat + (size_t)N_GRAPHS * DIM;   // 2
    int* counts    = (int*)(mm + 2);               // N
    int* cursor    = counts + N_NODES;             // N
    int* row_start = cursor + N_NODES;             // N+1
    int2* epack    = (int2*)(row_start + N_NODES + 2); // E (8B aligned)

    // CSR build (shared by both GINE layers — same dst)
    hipMemsetAsync(counts, 0, N_NODES * sizeof(int), stream);
    hist_k<<<N_EDGES / 256, 256, 0, stream>>>(dst, counts);
    scan_k<<<1, 1024, 0, stream>>>(counts, row_start, cursor);
    fill_k<<<N_EDGES / 256, 256, 0, stream>>>(src, dst, length, cursor, epack);

    node_embed_k<<<N_NODES / 16, 256, 0, stream>>>(atomic_num, W_node, b_node, h0);

    // GINE layer 0
    gather_agg_k<<<N_NODES / 4, 256, 0, stream>>>(
        h0, row_start, epack, W_edge, b_edge, gine_eps, 0, x);
    node_update_k<<<N_NODES / 16, 256, 0, stream>>>(x, h1, W_gnn, b_gnn);

    // GINE layer 1
    gather_agg_k<<<N_NODES / 4, 256, 0, stream>>>(
        h1, row_start, epack, W_edge, b_edge, gine_eps, 1, x);
    node_update_k<<<N_NODES / 16, 256, 0, stream>>>(x, h0, W_gnn + DIM * DIM, b_gnn + DIM);

    // pooling + normalize + head
    pool_k<<<N_GRAPHS, 256, 0, stream>>>(h0, gid, feat);
    minmax_k<<<1, 256, 0, stream>>>(feat, mm);
    head_k<<<(N_GRAPHS * OUTD + 255) / 256, 256, 0, stream>>>(
        feat, mm, W_mlp, b_mlp, out, eps_param);
}

// Round 3
// 364.643 us; speedup vs baseline: 6.6902x; 1.1370x over previous
//
#include <hip/hip_runtime.h>
#include <hip/hip_bf16.h>

#define N_NODES 10000
#define N_EDGES 320000
#define N_GRAPHS 64
#define DIM 256
#define ADIM 118
#define OUTD 100

// ---------- node embedding: h = atomic_num @ W_node + b_node ----------
__global__ __launch_bounds__(256) void node_embed_k(
    const float* __restrict__ an, const float* __restrict__ Wn,
    const float* __restrict__ bn, float* __restrict__ h) {
    __shared__ float xs[16][ADIM + 2];
    const int block_row = blockIdx.x * 16;
    const int tid = threadIdx.x;
    #pragma unroll
    for (int r = 0; r < 16; ++r) {
        if (tid < ADIM) xs[r][tid] = an[(block_row + r) * ADIM + tid];
    }
    __syncthreads();
    float acc[16];
    #pragma unroll
    for (int m = 0; m < 16; ++m) acc[m] = 0.f;
    for (int k = 0; k < ADIM; ++k) {
        float w = Wn[k * DIM + tid];
        #pragma unroll
        for (int m = 0; m < 16; ++m) acc[m] += xs[m][k] * w;
    }
    float bb = bn[tid];
    #pragma unroll
    for (int m = 0; m < 16; ++m)
        h[(block_row + m) * DIM + tid] = acc[m] + bb;
}

// ---------- CSR build ----------
__global__ __launch_bounds__(256) void hist_k(
    const int* __restrict__ dst, int* __restrict__ counts) {
    int j = blockIdx.x * 256 + threadIdx.x;
    if (j < N_EDGES) atomicAdd(&counts[dst[j]], 1);
}

// single-block exclusive scan, shfl-based (wave=64)
__global__ __launch_bounds__(1024) void scan_k(
    const int* __restrict__ counts, int* __restrict__ row_start,
    int* __restrict__ cursor) {
    __shared__ int wsum[16];
    __shared__ int s_total;
    __shared__ int carry;
    const int tid = threadIdx.x;
    const int lane = tid & 63;
    const int wave = tid >> 6;
    if (tid == 0) carry = 0;
    __syncthreads();
    for (int base = 0; base < N_NODES; base += 1024) {
        int i = base + tid;
        int v = (i < N_NODES) ? counts[i] : 0;
        // inclusive scan within wave
        int x = v;
        #pragma unroll
        for (int off = 1; off < 64; off <<= 1) {
            int t = __shfl_up(x, off, 64);
            if (lane >= off) x += t;
        }
        if (lane == 63) wsum[wave] = x;
        __syncthreads();
        if (wave == 0 && lane < 16) {
            int ws = wsum[lane];
            int y = ws;
            #pragma unroll
            for (int off = 1; off < 16; off <<= 1) {
                int t = __shfl_up(y, off, 64);
                if (lane >= off) y += t;
            }
            wsum[lane] = y - ws;          // exclusive wave offset
            if (lane == 15) s_total = y;  // tile total
        }
        __syncthreads();
        if (i < N_NODES) {
            int e = carry + wsum[wave] + x - v;
            row_start[i] = e;
            cursor[i] = e;
        }
        __syncthreads();
        if (tid == 0) carry += s_total;
        __syncthreads();
    }
    if (tid == 0) row_start[N_NODES] = carry;
}

// pack (src, length-bits) into CSR slots
__global__ __launch_bounds__(256) void fill_k(
    const int* __restrict__ src, const int* __restrict__ dst,
    const float* __restrict__ len, int* __restrict__ cursor,
    int2* __restrict__ epack) {
    int j = blockIdx.x * 256 + threadIdx.x;
    if (j >= N_EDGES) return;
    int d = dst[j];
    int pos = atomicAdd(&cursor[d], 1);
    epack[pos] = make_int2(src[j], __float_as_int(len[j]));
}

// ---------- fused gather-aggregate ----------
__global__ __launch_bounds__(256) void gather_agg_k(
    const float* __restrict__ h, const int* __restrict__ row_start,
    const int2* __restrict__ epack, const float* __restrict__ We,
    const float* __restrict__ be, const float* __restrict__ epsp, int layer,
    float* __restrict__ x) {
    const int node = blockIdx.x * 4 + (threadIdx.x >> 6);
    const int lane = threadIdx.x & 63;
    const int c = lane << 2;
    const float4 w  = *(const float4*)(We + c);
    const float4 bb = *(const float4*)(be + c);
    float4 acc = {0.f, 0.f, 0.f, 0.f};
    const int lo = row_start[node];
    const int hi = row_start[node + 1];
    for (int b = lo; b < hi; b += 64) {
        int cnt = min(64, hi - b);
        int sj = 0;
        float lj = 0.f;
        if (lane < cnt) {
            int2 p = epack[b + lane];
            sj = p.x;
            lj = __int_as_float(p.y);
        }
        for (int t = 0; t < cnt; ++t) {
            int s   = __shfl(sj, t, 64);
            float l = __shfl(lj, t, 64);
            const float4 hv = *(const float4*)(h + (size_t)s * DIM + c);
            acc.x += fmaxf(hv.x + l * w.x + bb.x, 0.f);
            acc.y += fmaxf(hv.y + l * w.y + bb.y, 0.f);
            acc.z += fmaxf(hv.z + l * w.z + bb.z, 0.f);
            acc.w += fmaxf(hv.w + l * w.w + bb.w, 0.f);
        }
    }
    const float eps1 = 1.f + epsp[layer];
    const float4 hv = *(const float4*)(h + (size_t)node * DIM + c);
    float4 xo;
    xo.x = eps1 * hv.x + acc.x;
    xo.y = eps1 * hv.y + acc.y;
    xo.z = eps1 * hv.z + acc.z;
    xo.w = eps1 * hv.w + acc.w;
    *(float4*)(x + (size_t)node * DIM + c) = xo;
}

// ---------- node update GEMM (+ optional fused pooling) ----------
__global__ __launch_bounds__(256) void node_update_k(
    const float* __restrict__ x, float* __restrict__ hout,
    const float* __restrict__ W, const float* __restrict__ b,
    const int* __restrict__ gid, float* __restrict__ feat, int do_pool) {
    __shared__ float xs[16][DIM];
    __shared__ int gids[16];
    const int block_row = blockIdx.x * 16;
    const int tid = threadIdx.x;
    #pragma unroll
    for (int i = 0; i < 16; ++i)
        xs[i][tid] = x[(block_row + i) * DIM + tid];
    if (do_pool && tid < 16) gids[tid] = gid[block_row + tid];
    __syncthreads();
    float acc[16];
    #pragma unroll
    for (int m = 0; m < 16; ++m) acc[m] = 0.f;
    for (int k = 0; k < DIM; ++k) {
        float w = W[k * DIM + tid];
        #pragma unroll
        for (int m = 0; m < 16; ++m) acc[m] += xs[m][k] * w;
    }
    float bb = b[tid];
    #pragma unroll
    for (int m = 0; m < 16; ++m)
        hout[(block_row + m) * DIM + tid] = acc[m] + bb;
    if (do_pool) {
        // run-length sum over sorted graph ids, 1 atomic per run per thread
        float run = 0.f;
        int cur = gids[0];
        #pragma unroll
        for (int m = 0; m < 16; ++m) {
            int g = gids[m];
            if (g != cur) {
                atomicAdd(&feat[cur * DIM + tid], run);
                run = 0.f;
                cur = g;
            }
            run += acc[m] + bb;
        }
        atomicAdd(&feat[cur * DIM + tid], run);
    }
}

__global__ __launch_bounds__(256) void minmax_k(
    const float* __restrict__ feat, float* __restrict__ mm) {
    float mn = 3.4e38f, mx = -3.4e38f;
    for (int i = threadIdx.x; i < N_GRAPHS * DIM; i += 256) {
        float v = feat[i];
        mn = fminf(mn, v);
        mx = fmaxf(mx, v);
    }
    #pragma unroll
    for (int off = 32; off > 0; off >>= 1) {
        mn = fminf(mn, __shfl_down(mn, off, 64));
        mx = fmaxf(mx, __shfl_down(mx, off, 64));
    }
    __shared__ float smn[4], smx[4];
    int wave = threadIdx.x >> 6;
    int lane = threadIdx.x & 63;
    if (lane == 0) { smn[wave] = mn; smx[wave] = mx; }
    __syncthreads();
    if (threadIdx.x == 0) {
        mn = smn[0]; mx = smx[0];
        #pragma unroll
        for (int w = 1; w < 4; ++w) {
            mn = fminf(mn, smn[w]);
            mx = fmaxf(mx, smx[w]);
        }
        mm[0] = mn;
        mm[1] = mx;
    }
}

__global__ __launch_bounds__(256) void head_k(
    const float* __restrict__ feat, const float* __restrict__ mm,
    const float* __restrict__ Wm, const float* __restrict__ bm,
    float* __restrict__ out, const float* __restrict__ epsp) {
    int tid = blockIdx.x * 256 + threadIdx.x;
    if (tid >= N_GRAPHS * OUTD) return;
    int g = tid / OUTD;
    int o = tid % OUTD;
    float mn = mm[0], mx = mm[1];
    float inv = 1.f / (epsp[0] + mx - mn);
    float acc = 0.f;
    for (int d = 0; d < DIM; ++d)
        acc += (feat[g * DIM + d] - mn) * Wm[d * OUTD + o];
    out[tid] = acc * inv + bm[o];
}

extern "C" void kernel_launch(void* const* d_in, const int* in_sizes, int n_in,
                              void* d_out, int out_size, void* d_ws, size_t ws_size,
                              hipStream_t stream) {
    const float* atomic_num = (const float*)d_in[0];
    const float* length     = (const float*)d_in[1];
    const int*   src        = (const int*)d_in[2];
    const int*   dst        = (const int*)d_in[3];
    const int*   gid        = (const int*)d_in[4];
    const float* W_node     = (const float*)d_in[5];
    const float* b_node     = (const float*)d_in[6];
    const float* W_edge     = (const float*)d_in[7];
    const float* b_edge     = (const float*)d_in[8];
    const float* gine_eps   = (const float*)d_in[9];
    const float* W_gnn      = (const float*)d_in[10];
    const float* b_gnn      = (const float*)d_in[11];
    const float* eps_param  = (const float*)d_in[12];
    const float* W_mlp      = (const float*)d_in[13];
    const float* b_mlp      = (const float*)d_in[14];
    float* out = (float*)d_out;

    float* h0   = (float*)d_ws;                    // N*D
    float* h1   = h0 + (size_t)N_NODES * DIM;      // N*D
    float* x    = h1 + (size_t)N_NODES * DIM;      // N*D
    float* feat = x + (size_t)N_NODES * DIM;       // G*D
    float* mm   = feat + (size_t)N_GRAPHS * DIM;   // 2
    int* counts    = (int*)(mm + 2);               // N
    int* cursor    = counts + N_NODES;             // N
    int* row_start = cursor + N_NODES;             // N+1
    int2* epack    = (int2*)(row_start + N_NODES + 2); // E

    // CSR build (dst is identical for both layers)
    hipMemsetAsync(counts, 0, N_NODES * sizeof(int), stream);
    hipMemsetAsync(feat, 0, N_GRAPHS * DIM * sizeof(float), stream);
    hist_k<<<N_EDGES / 256, 256, 0, stream>>>(dst, counts);
    scan_k<<<1, 1024, 0, stream>>>(counts, row_start, cursor);
    fill_k<<<N_EDGES / 256, 256, 0, stream>>>(src, dst, length, cursor, epack);

    node_embed_k<<<N_NODES / 16, 256, 0, stream>>>(atomic_num, W_node, b_node, h0);

    // GINE layer 0
    gather_agg_k<<<N_NODES / 4, 256, 0, stream>>>(
        h0, row_start, epack, W_edge, b_edge, gine_eps, 0, x);
    node_update_k<<<N_NODES / 16, 256, 0, stream>>>(
        x, h1, W_gnn, b_gnn, gid, feat, 0);

    // GINE layer 1 (pooling fused into the update GEMM)
    gather_agg_k<<<N_NODES / 4, 256, 0, stream>>>(
        h1, row_start, epack, W_edge, b_edge, gine_eps, 1, x);
    node_update_k<<<N_NODES / 16, 256, 0, stream>>>(
        x, h0, W_gnn + DIM * DIM, b_gnn + DIM, gid, feat, 1);

    // normalize + head
    minmax_k<<<1, 256, 0, stream>>>(feat, mm);
    head_k<<<(N_GRAPHS * OUTD + 255) / 256, 256, 0, stream>>>(
        feat, mm, W_mlp, b_mlp, out, eps_param);
}